// Round 1
// baseline (607.790 us; speedup 1.0000x reference)
//
#include <hip/hip_runtime.h>
#include <math.h>

// Problem constants (fixed by setup_inputs): B=64, Q=1024, N=2048, C=2048, P=512, WIN=256
#define Bb  64
#define Qq  1024
#define Nn  2048
#define Cc  2048
#define Pp  512
#define WIN 256

// Key reduction: softmax over the SINGLETON axis of (B,W,1) == 1.0 for finite
// scores, and the window is guaranteed in-bounds (no -inf/NaN path), so the
// whole w_a / proj / a_t branch is dead. Output is just:
//   s_t[b,q] = sum_k exp(-2*((p-128+k - p_t)/128)^2) * q_i[b, q, p-128+k]
// with p_t = 2047*sigmoid(sum_p v_p[p]*tanh(dot(c_t[b], w_p[p]))), p=rint(p_t).

// ---------------- k0: transpose c_t (64x2048) -> ct_T (2048x64) -------------
// Fixes k1a's pathological per-lane 8KB-stride gather (64 cache lines per
// load instruction) by making the batch dim contiguous.
__global__ __launch_bounds__(256) void k0_tr(const float* __restrict__ c_t,
                                             float* __restrict__ ct_T) {
  __shared__ float tile[64][65];  // +1 pad: conflict-free column writes
  const int c0 = blockIdx.x << 6;  // 32 blocks x 64 c-columns
  const int t = threadIdx.x;
  const int tc = t & 63;
  const int tb0 = t >> 6;  // 0..3
#pragma unroll
  for (int j = 0; j < 16; ++j) {
    const int b = (j << 2) + tb0;
    tile[tc][b] = c_t[(size_t)b * Cc + c0 + tc];  // coalesced along c
  }
  __syncthreads();
#pragma unroll
  for (int j = 0; j < 16; ++j) {
    const int cc = (j << 2) + tb0;
    ct_T[(size_t)(c0 + cc) * 64 + tc] = tile[cc][tc];  // coalesced along b
  }
}

// ---------------- k1a: partial GEMV  d[b,p] = dot(c_t[b,:], w_p[p,:]) -------
// grid 512 = 64 p-chunks (8 rows) x 8 kcb; block 256 = 4 waves, wave kc = kcb*4+w
// lane = batch. w_p addresses are wave-uniform -> scalar loads; c_t now read
// through ct_T so each per-lane load is one coalesced 256B transaction.
__global__ __launch_bounds__(256) void k1a_gemv(const float* __restrict__ ct_T,
                                                const float* __restrict__ w_p,
                                                float* __restrict__ partial) {
  const int pc   = blockIdx.x >> 3;     // 0..63
  const int kcb  = blockIdx.x & 7;      // 0..7
  const int w    = threadIdx.x >> 6;    // 0..3
  const int lane = threadIdx.x & 63;    // batch index
  const int kc   = __builtin_amdgcn_readfirstlane(kcb * 4 + w); // 0..31 (uniform)
  const int c0   = kc * 64;
  const int p0   = pc * 8;
  float acc[8] = {0.f, 0.f, 0.f, 0.f, 0.f, 0.f, 0.f, 0.f};
#pragma unroll 4
  for (int cq = 0; cq < 16; ++cq) {
    const int c = c0 + (cq << 2);
    const float cvx = ct_T[(size_t)(c + 0) * 64 + lane];
    const float cvy = ct_T[(size_t)(c + 1) * 64 + lane];
    const float cvz = ct_T[(size_t)(c + 2) * 64 + lane];
    const float cvw = ct_T[(size_t)(c + 3) * 64 + lane];
#pragma unroll
    for (int i = 0; i < 8; ++i) {
      const float4 wv =
          *reinterpret_cast<const float4*>(w_p + (size_t)(p0 + i) * Cc + c);
      acc[i] = fmaf(cvx, wv.x, acc[i]);
      acc[i] = fmaf(cvy, wv.y, acc[i]);
      acc[i] = fmaf(cvz, wv.z, acc[i]);
      acc[i] = fmaf(cvw, wv.w, acc[i]);
    }
  }
  // combine the block's 4 waves (4 consecutive kc) -> one kcb partial
  __shared__ float red[4][8][64];
#pragma unroll
  for (int i = 0; i < 8; ++i) red[w][i][lane] = acc[i];
  __syncthreads();
#pragma unroll
  for (int j = 0; j < 2; ++j) {
    const int idx = threadIdx.x + 256 * j;  // 0..511 = 8p x 64b
    const int pi = idx >> 6, bb = idx & 63;
    const float s =
        red[0][pi][bb] + red[1][pi][bb] + red[2][pi][bb] + red[3][pi][bb];
    partial[(size_t)((bb << 9) + p0 + pi) * 8 + kcb] = s;
  }
}

// ---------------- k1b: finish p_t, emit gaussian weights + base -------------
// Weights stored TRANSPOSED: gt[b][ (k&63)*4 + (k>>6) ] = g[k], so k2 can
// fetch its 4 per-lane weights with a single float4 load.
__global__ __launch_bounds__(256) void k1b_finish(const float* __restrict__ partial,
                                                  const float* __restrict__ v_p,
                                                  float* __restrict__ gt,
                                                  int* __restrict__ basei) {
  const int b = blockIdx.x;
  const int t = threadIdx.x;
  float zs = 0.f;
#pragma unroll
  for (int j = 0; j < 2; ++j) {
    const int p = t + 256 * j;
    const float4* pp =
        reinterpret_cast<const float4*>(partial + (size_t)(b * Pp + p) * 8);
    const float4 a = pp[0], c = pp[1];
    const float d = ((a.x + a.y) + (a.z + a.w)) + ((c.x + c.y) + (c.z + c.w));
    zs += tanhf(d) * v_p[p];
  }
  __shared__ float red[256];
  red[t] = zs;
  __syncthreads();
  for (int s = 128; s > 0; s >>= 1) {
    if (t < s) red[t] += red[t + s];
    __syncthreads();
  }
  __shared__ float spt;
  __shared__ int sbase;
  if (t == 0) {
    const float z = red[0];
    const float loc = 1.f / (1.f + expf(-z));
    const float pt = loc * 2047.f;           // loc * (size-2), size = N+1
    const int p = (int)rintf(pt);            // round-half-even == jnp.round
    const int base = p - 128;                // n = base + k, k in [0,256)
    int bc = base < 0 ? 0 : base;            // safety clamp (never hit in-bounds)
    if (bc > Nn - WIN) bc = Nn - WIN;
    spt = pt;
    sbase = base;
    basei[b] = bc;
  }
  __syncthreads();
  const float pt = spt;
  const float d = ((float)(sbase + t) - pt) * (1.f / 128.f);
  gt[(b << 8) + ((t & 63) << 2) + (t >> 6)] = expf(-2.f * d * d);
}

// ---------------- k2: gathered weighted sum (memory-bound main kernel) ------
// one wave per 4 rows; lane l covers window offsets l+64j (4B-aligned dword
// loads, each a perfectly coalesced 256B transaction). Merged pairwise
// butterfly reduction: 7 shfl per 2 rows instead of 12.
__global__ __launch_bounds__(256) void k2_gather(const float* __restrict__ q,
                                                 const float* __restrict__ gt,
                                                 const int* __restrict__ basei,
                                                 float* __restrict__ out) {
  const int wave = (blockIdx.x * 256 + threadIdx.x) >> 6;  // 0..16383
  const int lane = threadIdx.x & 63;
  const int r0 = wave << 2;       // 4 rows per wave (same batch: 1024 % 4 == 0)
  const int b = r0 >> 10;
  const int base = basei[b];
  const float4 gv =
      *reinterpret_cast<const float4*>(gt + (b << 8) + (lane << 2));
  float acc[4];
#pragma unroll
  for (int rr = 0; rr < 4; ++rr) {
    const float* row = q + ((size_t)(r0 + rr) << 11) + base;
    float a = gv.x * row[lane];
    a = fmaf(gv.y, row[lane + 64], a);
    a = fmaf(gv.z, row[lane + 128], a);
    a = fmaf(gv.w, row[lane + 192], a);
    acc[rr] = a;
  }
  // merged reduction: rows (0,1) share one butterfly, rows (2,3) the other.
  float a0 = acc[0], a1 = acc[1], a2 = acc[2], a3 = acc[3];
  a0 += __shfl_xor(a0, 32, 64);
  a1 += __shfl_xor(a1, 32, 64);
  a2 += __shfl_xor(a2, 32, 64);
  a3 += __shfl_xor(a3, 32, 64);
  float v1 = (lane < 32) ? a0 : a1;  // lanes 0-31: row0 partials; 32-63: row1
  float v2 = (lane < 32) ? a2 : a3;
#pragma unroll
  for (int off = 16; off > 0; off >>= 1) {
    v1 += __shfl_xor(v1, off, 64);
    v2 += __shfl_xor(v2, off, 64);
  }
  if (lane == 0) {
    out[r0] = v1;
    out[r0 + 2] = v2;
  }
  if (lane == 32) {
    out[r0 + 1] = v1;
    out[r0 + 3] = v2;
  }
}

extern "C" void kernel_launch(void* const* d_in, const int* in_sizes, int n_in,
                              void* d_out, int out_size, void* d_ws, size_t ws_size,
                              hipStream_t stream) {
  const float* q_i = (const float*)d_in[0];
  const float* c_t = (const float*)d_in[1];
  // d_in[2] = w_a : dead code (softmax over singleton axis == 1)
  const float* w_p = (const float*)d_in[3];
  const float* v_p = (const float*)d_in[4];
  // d_in[5] = window (==256, baked into WIN)
  float* out = (float*)d_out;

  // ws layout: partial [64][512][8] f32 (1MB) | gt [64][256] f32 | base [64] i32
  //            | ct_T [2048][64] f32 (512KB)
  float* partial = (float*)d_ws;
  float* gt = partial + (size_t)Bb * Pp * 8;
  int* basei = (int*)(gt + Bb * 256);
  float* ct_T = (float*)(basei + Bb);

  k0_tr<<<32, 256, 0, stream>>>(c_t, ct_T);
  k1a_gemv<<<512, 256, 0, stream>>>(ct_T, w_p, partial);
  k1b_finish<<<Bb, 256, 0, stream>>>(partial, v_p, gt, basei);
  k2_gather<<<4096, 256, 0, stream>>>(q_i, gt, basei, out);
}